// Round 4
// baseline (96.027 us; speedup 1.0000x reference)
//
#include <hip/hip_runtime.h>
#include <hip/hip_bf16.h>

typedef __attribute__((ext_vector_type(8))) short bf16x8;
typedef __attribute__((ext_vector_type(4))) float f32x4;
typedef unsigned int u32;
typedef unsigned short u16;

#define NPOS 147456      // 384*384
#define NTILES 9216      // NPOS/16
#define NBLK (NTILES / 4)  // 2304 blocks of 4 waves, 1 tile per wave

__device__ inline u16 bfc(float f) {
  union { __hip_bfloat16 h; u16 s; } u;
  u.h = __float2bfloat16(f);
  return u.s;
}

// ---------------------------------------------------------------------------
// Prologue: bake bf16 weight fragments into ws, in exact MFMA lane layout.
// ws layout in u16 units (frag = 512 u16 = 64 lanes x 8 elems):
//   frags  0..15 : wq  (n*4+kc), Wq^T * 0.25
//   frags 16..23 : wk  (n*2+kc)
//   frags 24..31 : wv  (n*2+kc)
//   frags 32..47 : wo  (n8*2+kc)
// Frag elem (lane,e): A[row=lane&15][k=(lane>>4)*8+e] of the 16x32 operand.
// ---------------------------------------------------------------------------
__global__ void prep_kernel(const float* __restrict__ wq, const float* __restrict__ wk,
                            const float* __restrict__ wv, const float* __restrict__ wo,
                            u16* __restrict__ wsf) {
  int gid = blockIdx.x * 256 + threadIdx.x;   // [0, 24576)
  int idx, which;
  if (gid < 8192)       { idx = gid;         which = 0; }
  else if (gid < 12288) { idx = gid - 8192;  which = 1; }
  else if (gid < 16384) { idx = gid - 12288; which = 2; }
  else                  { idx = gid - 16384; which = 3; }
  int fragid = idx >> 9, lane = (idx >> 3) & 63, e = idx & 7;
  int l15 = lane & 15, g = lane >> 4;
  float v;
  if (which == 0) {        // wq: [4][128][16], A[row=d][k=c]
    int n = fragid >> 2, kc = fragid & 3;
    int c = kc * 32 + g * 8 + e;
    v = wq[n * 2048 + c * 16 + l15] * 0.25f;   // fold D^-0.5
  } else if (which == 1) { // wk: [4][64][16], A[row=d][k=c]
    int n = fragid >> 1, kc = fragid & 1;
    int c = kc * 32 + g * 8 + e;
    v = wk[n * 1024 + c * 16 + l15];
  } else if (which == 2) { // wv
    int n = fragid >> 1, kc = fragid & 1;
    int c = kc * 32 + g * 8 + e;
    v = wv[n * 1024 + c * 16 + l15];
  } else {                 // wo: [4][16][128], A[row=cq-sub][k=hd]
    int n8 = fragid >> 1, kc = fragid & 1;
    int hd = kc * 32 + g * 8 + e;
    v = wo[(hd >> 4) * 2048 + (hd & 15) * 128 + n8 * 16 + l15];
  }
  wsf[gid] = bfc(v);
}

// frag ids in wlds
#define WQF(n, kc)  ((n) * 4 + (kc))
#define WKF(n, kc)  (16 + (n) * 2 + (kc))
#define WVF(n, kc)  (24 + (n) * 2 + (kc))
#define WOF(n8, kc) (32 + (n8) * 2 + (kc))

// ---------------------------------------------------------------------------
// Main: 4-wave blocks; 48 KB weight frags staged once per block into LDS;
// one 16-position tile per wave; frag reads are ds_read_b128.
// ---------------------------------------------------------------------------
__global__ __launch_bounds__(256, 3) void tpa_kernel(
    const float* __restrict__ qe, const float* __restrict__ tpr,
    const float* __restrict__ tmk_p, const float* __restrict__ ob,
    const u16* __restrict__ wsf, float* __restrict__ out)
{
  __shared__ int4 wlds4[3072];                 // 48 KB
  u16* wlds = (u16*)wlds4;

  const int tid = threadIdx.x;
  const int wid = tid >> 6;
  const int lane = tid & 63;
  const int l15 = lane & 15, g = lane >> 4;
  const int p0 = (blockIdx.x * 4 + wid) * 16;

#define FR(f) (*reinterpret_cast<const bf16x8*>(&wlds[(f) * 512 + lane * 8]))

  // ---- issue this wave's q + t0/t1 HBM loads first (independent of LDS) ----
  const f32x4* qbase = reinterpret_cast<const f32x4*>(qe) + (p0 + l15) * 32 + g * 2;
  f32x4 qv[8];
  #pragma unroll
  for (int kc = 0; kc < 4; ++kc) {
    qv[kc * 2 + 0] = qbase[kc * 8 + 0];
    qv[kc * 2 + 1] = qbase[kc * 8 + 1];
  }

#define LOADT(buf, t)                                                          \
  {                                                                            \
    const f32x4* tb = reinterpret_cast<const f32x4*>(tpr) +                    \
                      ((size_t)(t) * NPOS + p0 + l15) * 16 + g * 2;            \
    buf[0] = tb[0]; buf[1] = tb[1]; buf[2] = tb[8]; buf[3] = tb[9];            \
  }

  f32x4 tva[4], tvb[4];
  LOADT(tva, 0)
  LOADT(tvb, 1)

  // ---- stage weight frags (pre-baked layout: straight 16B copies) ----
  {
    const int4* src = (const int4*)wsf;
    #pragma unroll
    for (int i = 0; i < 12; ++i) wlds4[tid + i * 256] = src[tid + i * 256];
  }

  const float m0 = tmk_p[0], m1 = tmk_p[1], m2 = tmk_p[2], m3 = tmk_p[3];
  const float biasv[4] = {65504.0f * (m0 - 1.0f), 65504.0f * (m1 - 1.0f),
                          65504.0f * (m2 - 1.0f), 65504.0f * (m3 - 1.0f)};
  const float tmk = (m0 + m1 + m2 + m3 > 0.0f) ? 1.0f : 0.0f;

  __syncthreads();

  // ---- GEMM1 (swapped): qT[n] = Q^T tile, lane = [d=g*4+r][pos=l15] ----
  f32x4 qT[4];
  #pragma unroll
  for (int n = 0; n < 4; ++n) qT[n] = (f32x4){0.f, 0.f, 0.f, 0.f};
  #pragma unroll
  for (int kc = 0; kc < 4; ++kc) {
    bf16x8 aq;
    #pragma unroll
    for (int e = 0; e < 8; ++e)
      aq[e] = (short)bfc(e < 4 ? qv[kc * 2 + 0][e] : qv[kc * 2 + 1][e - 4]);
    #pragma unroll
    for (int n = 0; n < 4; ++n)
      qT[n] = __builtin_amdgcn_mfma_f32_16x16x32_bf16(FR(WQF(n, kc)), aq, qT[n], 0, 0, 0);
  }

  // ---- template loop (explicitly unrolled, double-buffered t rows) ----
  float ssum[4] = {0.f, 0.f, 0.f, 0.f};
  f32x4 wvT[4];
  #pragma unroll
  for (int n = 0; n < 4; ++n) wvT[n] = (f32x4){0.f, 0.f, 0.f, 0.f};

#define CVT2(at0, at1, buf)                                                    \
  {                                                                            \
    _Pragma("unroll")                                                          \
    for (int e = 0; e < 8; ++e) {                                              \
      at0[e] = (short)bfc(e < 4 ? buf[0][e] : buf[1][e - 4]);                  \
      at1[e] = (short)bfc(e < 4 ? buf[2][e] : buf[3][e - 4]);                  \
    }                                                                          \
  }

#define TSTEP(at0, at1, bias)                                                  \
  {                                                                            \
    _Pragma("unroll")                                                          \
    for (int n = 0; n < 4; ++n) {                                              \
      f32x4 kT = (f32x4){0.f, 0.f, 0.f, 0.f};                                  \
      f32x4 vT = (f32x4){0.f, 0.f, 0.f, 0.f};                                  \
      kT = __builtin_amdgcn_mfma_f32_16x16x32_bf16(FR(WKF(n, 0)), at0, kT, 0, 0, 0); \
      kT = __builtin_amdgcn_mfma_f32_16x16x32_bf16(FR(WKF(n, 1)), at1, kT, 0, 0, 0); \
      vT = __builtin_amdgcn_mfma_f32_16x16x32_bf16(FR(WVF(n, 0)), at0, vT, 0, 0, 0); \
      vT = __builtin_amdgcn_mfma_f32_16x16x32_bf16(FR(WVF(n, 1)), at1, vT, 0, 0, 0); \
      float lg = qT[n][0] * kT[0] + qT[n][1] * kT[1] + qT[n][2] * kT[2] + qT[n][3] * kT[3]; \
      lg += __shfl_xor(lg, 16);                                                \
      lg += __shfl_xor(lg, 32);                                                \
      const float w = __expf(lg + (bias));                                     \
      ssum[n] += w;                                                            \
      _Pragma("unroll")                                                        \
      for (int r = 0; r < 4; ++r) wvT[n][r] += w * vT[r];                      \
    }                                                                          \
  }

  {
    bf16x8 at0, at1;
    CVT2(at0, at1, tva)          // frees tva's f32 regs
    LOADT(tva, 2)                // prefetch t=2 into freed buffer
    TSTEP(at0, at1, biasv[0])
  }
  {
    bf16x8 at0, at1;
    CVT2(at0, at1, tvb)
    LOADT(tvb, 3)
    TSTEP(at0, at1, biasv[1])
  }
  {
    bf16x8 at0, at1;
    CVT2(at0, at1, tva)
    TSTEP(at0, at1, biasv[2])
  }
  {
    bf16x8 at0, at1;
    CVT2(at0, at1, tvb)
    TSTEP(at0, at1, biasv[3])
  }

  // ---- normalize + pack to bf16 pairs ----
  u32 pk[4][2];
  #pragma unroll
  for (int n = 0; n < 4; ++n) {
    const float inv = tmk / fmaxf(ssum[n], 1e-30f);
    pk[n][0] = (u32)bfc(wvT[n][0] * inv) | ((u32)bfc(wvT[n][1] * inv) << 16);
    pk[n][1] = (u32)bfc(wvT[n][2] * inv) | ((u32)bfc(wvT[n][3] * inv) << 16);
  }

  // ---- transpose WV[d][pos] -> frag WV[pos][hd] via shfl ----
  union { u32 w[4]; bf16x8 v; } awv[2];
  #pragma unroll
  for (int kc = 0; kc < 2; ++kc)
    #pragma unroll
    for (int w = 0; w < 4; ++w) {
      const int j = w & 1, hi = w >> 1;
      const int src = l15 + 16 * ((g & 1) * 2 + hi);
      const u32 t0 = __shfl(pk[kc * 2 + 0][j], src);
      const u32 t1 = __shfl(pk[kc * 2 + 1][j], src);
      awv[kc].w[w] = (g >> 1) ? t1 : t0;
    }

  // ---- GEMM4 (both operands in frag layout) + f32x4 store ----
  const f32x4* obase = reinterpret_cast<const f32x4*>(ob);
  f32x4* orow = reinterpret_cast<f32x4*>(out + (size_t)(p0 + l15) * 128);
  #pragma unroll
  for (int n8 = 0; n8 < 8; ++n8) {
    f32x4 acc = (f32x4){0.f, 0.f, 0.f, 0.f};
    acc = __builtin_amdgcn_mfma_f32_16x16x32_bf16(FR(WOF(n8, 0)), awv[0].v, acc, 0, 0, 0);
    acc = __builtin_amdgcn_mfma_f32_16x16x32_bf16(FR(WOF(n8, 1)), awv[1].v, acc, 0, 0, 0);
    const f32x4 obf = obase[n8 * 4 + g];    // ob[n8*16+g*4 .. +4)
    f32x4 res;
    #pragma unroll
    for (int r = 0; r < 4; ++r) res[r] = acc[r] + obf[r] * tmk;
    orow[n8 * 4 + g] = res;                 // out[p0+l15][n8*16+g*4 .. +4)
  }
}

extern "C" void kernel_launch(void* const* d_in, const int* in_sizes, int n_in,
                              void* d_out, int out_size, void* d_ws, size_t ws_size,
                              hipStream_t stream) {
  const float* qe  = (const float*)d_in[0];
  const float* tpr = (const float*)d_in[1];
  const float* tmk = (const float*)d_in[2];
  const float* wq  = (const float*)d_in[3];
  const float* wk  = (const float*)d_in[4];
  const float* wv  = (const float*)d_in[5];
  const float* wo  = (const float*)d_in[6];
  const float* ob  = (const float*)d_in[7];
  float* out = (float*)d_out;
  u16* wsf = (u16*)d_ws;

  prep_kernel<<<96, 256, 0, stream>>>(wq, wk, wv, wo, wsf);
  tpa_kernel<<<NBLK, 256, 0, stream>>>(qe, tpr, tmk, ob, wsf, out);
}

// Round 5
// 84.329 us; speedup vs baseline: 1.1387x; 1.1387x over previous
//
#include <hip/hip_runtime.h>
#include <hip/hip_bf16.h>

typedef __attribute__((ext_vector_type(8))) short bf16x8;
typedef __attribute__((ext_vector_type(4))) float f32x4;
typedef unsigned int u32;
typedef unsigned short u16;

#define NPOS 147456        // 384*384
#define NTILES 9216        // NPOS/16
#define NBLK 512           // 2 blocks/CU
#define NWAVES (NBLK * 4)  // 2048 waves; each does 4-5 tiles (grid-stride)

__device__ inline u16 bfc(float f) {
  union { __hip_bfloat16 h; u16 s; } u;
  u.h = __float2bfloat16(f);
  return u.s;
}

// ---------------------------------------------------------------------------
// Prologue: bake bf16 weight fragments into ws, in exact MFMA lane layout.
// ws layout in u16 units (frag = 512 u16 = 64 lanes x 8 elems):
//   frags  0..15 : wq (n*4+kc)  Wq^T * 0.25
//   frags 16..23 : wk (n*2+kc)
//   frags 24..31 : wv (n*2+kc)
//   frags 32..47 : wo (n8*2+kc)
// Frag elem (lane,e): A[row=lane&15][k=(lane>>4)*8+e] of the 16x32 operand.
// ---------------------------------------------------------------------------
__global__ void prep_kernel(const float* __restrict__ wq, const float* __restrict__ wk,
                            const float* __restrict__ wv, const float* __restrict__ wo,
                            u16* __restrict__ wsf) {
  int gid = blockIdx.x * 256 + threadIdx.x;   // [0, 24576)
  int idx, which;
  if (gid < 8192)       { idx = gid;         which = 0; }
  else if (gid < 12288) { idx = gid - 8192;  which = 1; }
  else if (gid < 16384) { idx = gid - 12288; which = 2; }
  else                  { idx = gid - 16384; which = 3; }
  int fragid = idx >> 9, lane = (idx >> 3) & 63, e = idx & 7;
  int l15 = lane & 15, g = lane >> 4;
  float v;
  if (which == 0) {        // wq: [4][128][16], A[row=d][k=c]
    int n = fragid >> 2, kc = fragid & 3;
    int c = kc * 32 + g * 8 + e;
    v = wq[n * 2048 + c * 16 + l15] * 0.25f;   // fold D^-0.5
  } else if (which == 1) { // wk: [4][64][16], A[row=d][k=c]
    int n = fragid >> 1, kc = fragid & 1;
    int c = kc * 32 + g * 8 + e;
    v = wk[n * 1024 + c * 16 + l15];
  } else if (which == 2) { // wv
    int n = fragid >> 1, kc = fragid & 1;
    int c = kc * 32 + g * 8 + e;
    v = wv[n * 1024 + c * 16 + l15];
  } else {                 // wo: [4][16][128], A[row=cq-sub][k=hd]
    int n8 = fragid >> 1, kc = fragid & 1;
    int hd = kc * 32 + g * 8 + e;
    v = wo[(hd >> 4) * 2048 + (hd & 15) * 128 + n8 * 16 + l15];
  }
  wsf[gid] = bfc(v);
}

// frag ids in LDS
#define WQF(n, kc)  ((n) * 4 + (kc))
#define WKF(n, kc)  (16 + (n) * 2 + (kc))
#define WVF(n, kc)  (24 + (n) * 2 + (kc))
#define WOF(n8, kc) (32 + (n8) * 2 + (kc))

// ---------------------------------------------------------------------------
// Main: 2048 long-lived waves; weights staged once into LDS; 4-5 tiles/wave
// with cross-tile prefetch (next tile's q + t0/t1 issued under current
// tile's t2/t3 MFMA + epilogue). No VGPR cap.
// ---------------------------------------------------------------------------
__global__ __launch_bounds__(256) void tpa_kernel(
    const float* __restrict__ qe, const float* __restrict__ tpr,
    const float* __restrict__ tmk_p, const float* __restrict__ ob,
    const u16* __restrict__ wsf, float* __restrict__ out)
{
  __shared__ int4 wlds4[3072];                 // 48 KB
  u16* wlds = (u16*)wlds4;

  const int tid = threadIdx.x;
  const int wid = tid >> 6;
  const int lane = tid & 63;
  const int l15 = lane & 15, g = lane >> 4;
  const int wvid = blockIdx.x * 4 + wid;       // 0..2047

#define FR(f) (*reinterpret_cast<const bf16x8*>(&wlds[(f) * 512 + lane * 8]))

#define LOADQ(buf, P)                                                          \
  {                                                                            \
    const f32x4* qb = reinterpret_cast<const f32x4*>(qe) + ((P) + l15) * 32 + g * 2; \
    _Pragma("unroll")                                                          \
    for (int kc = 0; kc < 4; ++kc) {                                           \
      buf[kc * 2 + 0] = qb[kc * 8 + 0];                                        \
      buf[kc * 2 + 1] = qb[kc * 8 + 1];                                        \
    }                                                                          \
  }

#define LOADT(buf, t, P)                                                       \
  {                                                                            \
    const f32x4* tb = reinterpret_cast<const f32x4*>(tpr) +                    \
                      ((size_t)(t) * NPOS + (P) + l15) * 16 + g * 2;           \
    buf[0] = tb[0]; buf[1] = tb[1]; buf[2] = tb[8]; buf[3] = tb[9];            \
  }

  // ---- prologue: first tile's loads in flight before/while staging LDS ----
  f32x4 qv[8], tva[4], tvb[4];
  {
    const int p0 = wvid * 16;
    LOADQ(qv, p0)
    LOADT(tva, 0, p0)
    LOADT(tvb, 1, p0)
  }
  {
    const int4* src = (const int4*)wsf;
    #pragma unroll
    for (int i = 0; i < 12; ++i) wlds4[tid + i * 256] = src[tid + i * 256];
  }

  const float m0 = tmk_p[0], m1 = tmk_p[1], m2 = tmk_p[2], m3 = tmk_p[3];
  const float biasv[4] = {65504.0f * (m0 - 1.0f), 65504.0f * (m1 - 1.0f),
                          65504.0f * (m2 - 1.0f), 65504.0f * (m3 - 1.0f)};
  const float tmk = (m0 + m1 + m2 + m3 > 0.0f) ? 1.0f : 0.0f;

  // ob hoisted out of the loop (keeps epilogue free of new vmem loads that
  // would force a vmcnt wait draining the cross-tile prefetch)
  f32x4 obf[8];
  {
    const f32x4* obase = reinterpret_cast<const f32x4*>(ob);
    #pragma unroll
    for (int n8 = 0; n8 < 8; ++n8) {
      const f32x4 o = obase[n8 * 4 + g];
      #pragma unroll
      for (int r = 0; r < 4; ++r) obf[n8][r] = o[r] * tmk;
    }
  }

  __syncthreads();   // weights staged (read-only afterwards)

#define CVT2(at0, at1, buf)                                                    \
  {                                                                            \
    _Pragma("unroll")                                                          \
    for (int e = 0; e < 8; ++e) {                                              \
      at0[e] = (short)bfc(e < 4 ? buf[0][e] : buf[1][e - 4]);                  \
      at1[e] = (short)bfc(e < 4 ? buf[2][e] : buf[3][e - 4]);                  \
    }                                                                          \
  }

#define TSTEP(at0, at1, bias)                                                  \
  {                                                                            \
    _Pragma("unroll")                                                          \
    for (int n = 0; n < 4; ++n) {                                              \
      f32x4 kT = (f32x4){0.f, 0.f, 0.f, 0.f};                                  \
      f32x4 vT = (f32x4){0.f, 0.f, 0.f, 0.f};                                  \
      kT = __builtin_amdgcn_mfma_f32_16x16x32_bf16(FR(WKF(n, 0)), at0, kT, 0, 0, 0); \
      kT = __builtin_amdgcn_mfma_f32_16x16x32_bf16(FR(WKF(n, 1)), at1, kT, 0, 0, 0); \
      vT = __builtin_amdgcn_mfma_f32_16x16x32_bf16(FR(WVF(n, 0)), at0, vT, 0, 0, 0); \
      vT = __builtin_amdgcn_mfma_f32_16x16x32_bf16(FR(WVF(n, 1)), at1, vT, 0, 0, 0); \
      float lg = qT[n][0] * kT[0] + qT[n][1] * kT[1] + qT[n][2] * kT[2] + qT[n][3] * kT[3]; \
      lg += __shfl_xor(lg, 16);                                                \
      lg += __shfl_xor(lg, 32);                                                \
      const float w = __expf(lg + (bias));                                     \
      ssum[n] += w;                                                            \
      _Pragma("unroll")                                                        \
      for (int r = 0; r < 4; ++r) wvT[n][r] += w * vT[r];                      \
    }                                                                          \
  }

  for (int tile = wvid; tile < NTILES; tile += NWAVES) {
    const int p0 = tile * 16;
    // clamped next-tile base: prefetch is UNCONDITIONAL so waitcnt counting
    // stays static; on the last iteration we re-load current (data unused).
    const int np0 = (tile + NWAVES < NTILES) ? (tile + NWAVES) * 16 : p0;

    // ---- GEMM1 (swapped): qT[n] = Q^T tile, lane = [d=g*4+r][pos=l15] ----
    f32x4 qT[4];
    #pragma unroll
    for (int n = 0; n < 4; ++n) qT[n] = (f32x4){0.f, 0.f, 0.f, 0.f};
    #pragma unroll
    for (int kc = 0; kc < 4; ++kc) {
      bf16x8 aq;
      #pragma unroll
      for (int e = 0; e < 8; ++e)
        aq[e] = (short)bfc(e < 4 ? qv[kc * 2 + 0][e] : qv[kc * 2 + 1][e - 4]);
      #pragma unroll
      for (int n = 0; n < 4; ++n)
        qT[n] = __builtin_amdgcn_mfma_f32_16x16x32_bf16(FR(WQF(n, kc)), aq, qT[n], 0, 0, 0);
    }

    float ssum[4] = {0.f, 0.f, 0.f, 0.f};
    f32x4 wvT[4];
    #pragma unroll
    for (int n = 0; n < 4; ++n) wvT[n] = (f32x4){0.f, 0.f, 0.f, 0.f};

    {
      bf16x8 at0, at1;
      CVT2(at0, at1, tva)            // frees tva
      LOADT(tva, 2, p0)              // within-tile prefetch t2
      TSTEP(at0, at1, biasv[0])
    }
    {
      bf16x8 at0, at1;
      CVT2(at0, at1, tvb)
      LOADT(tvb, 3, p0)              // within-tile prefetch t3
      TSTEP(at0, at1, biasv[1])
    }
    {
      bf16x8 at0, at1;
      CVT2(at0, at1, tva)
      LOADQ(qv, np0)                 // cross-tile prefetch q'
      TSTEP(at0, at1, biasv[2])
    }
    {
      bf16x8 at0, at1;
      CVT2(at0, at1, tvb)
      LOADT(tva, 0, np0)             // cross-tile prefetch t0'
      LOADT(tvb, 1, np0)             // cross-tile prefetch t1'
      TSTEP(at0, at1, biasv[3])
    }

    // ---- normalize + pack to bf16 pairs ----
    u32 pk[4][2];
    #pragma unroll
    for (int n = 0; n < 4; ++n) {
      const float inv = tmk / fmaxf(ssum[n], 1e-30f);
      pk[n][0] = (u32)bfc(wvT[n][0] * inv) | ((u32)bfc(wvT[n][1] * inv) << 16);
      pk[n][1] = (u32)bfc(wvT[n][2] * inv) | ((u32)bfc(wvT[n][3] * inv) << 16);
    }

    // ---- transpose WV[d][pos] -> frag WV[pos][hd] via shfl ----
    union { u32 w[4]; bf16x8 v; } awv[2];
    #pragma unroll
    for (int kc = 0; kc < 2; ++kc)
      #pragma unroll
      for (int w = 0; w < 4; ++w) {
        const int j = w & 1, hi = w >> 1;
        const int src = l15 + 16 * ((g & 1) * 2 + hi);
        const u32 t0 = __shfl(pk[kc * 2 + 0][j], src);
        const u32 t1 = __shfl(pk[kc * 2 + 1][j], src);
        awv[kc].w[w] = (g >> 1) ? t1 : t0;
      }

    // ---- GEMM4 (both operands in frag layout) + f32x4 store ----
    f32x4* orow = reinterpret_cast<f32x4*>(out + (size_t)(p0 + l15) * 128);
    #pragma unroll
    for (int n8 = 0; n8 < 8; ++n8) {
      f32x4 acc = (f32x4){0.f, 0.f, 0.f, 0.f};
      acc = __builtin_amdgcn_mfma_f32_16x16x32_bf16(FR(WOF(n8, 0)), awv[0].v, acc, 0, 0, 0);
      acc = __builtin_amdgcn_mfma_f32_16x16x32_bf16(FR(WOF(n8, 1)), awv[1].v, acc, 0, 0, 0);
      f32x4 res;
      #pragma unroll
      for (int r = 0; r < 4; ++r) res[r] = acc[r] + obf[n8][r];
      orow[n8 * 4 + g] = res;        // out[p0+l15][n8*16+g*4 .. +4)
    }
  }
}

extern "C" void kernel_launch(void* const* d_in, const int* in_sizes, int n_in,
                              void* d_out, int out_size, void* d_ws, size_t ws_size,
                              hipStream_t stream) {
  const float* qe  = (const float*)d_in[0];
  const float* tpr = (const float*)d_in[1];
  const float* tmk = (const float*)d_in[2];
  const float* wq  = (const float*)d_in[3];
  const float* wk  = (const float*)d_in[4];
  const float* wv  = (const float*)d_in[5];
  const float* wo  = (const float*)d_in[6];
  const float* ob  = (const float*)d_in[7];
  float* out = (float*)d_out;
  u16* wsf = (u16*)d_ws;

  prep_kernel<<<96, 256, 0, stream>>>(wq, wk, wv, wo, wsf);
  tpa_kernel<<<NBLK, 256, 0, stream>>>(qe, tpr, tmk, ob, wsf, out);
}

// Round 6
// 64.440 us; speedup vs baseline: 1.4902x; 1.3086x over previous
//
#include <hip/hip_runtime.h>
#include <hip/hip_bf16.h>

typedef __attribute__((ext_vector_type(8))) short bf16x8;
typedef __attribute__((ext_vector_type(4))) float f32x4;
typedef unsigned int u32;
typedef unsigned short u16;

#define NPOS 147456
#define NTILES 9216
#define NBLK 768           // 3 blocks/CU
#define ITERS 12           // NTILES / NBLK (exact)

__device__ inline u16 bfc(float f) {
  union { __hip_bfloat16 h; u16 s; } u;
  u.h = __float2bfloat16(f);
  return u.s;
}

// ---------------------------------------------------------------------------
// Prologue: bake bf16 weight fragments into ws (unchanged from R3-R5).
// frag = 512 u16; frag elem (lane,e): A[row=lane&15][k=(lane>>4)*8+e].
// ---------------------------------------------------------------------------
__global__ void prep_kernel(const float* __restrict__ wq, const float* __restrict__ wk,
                            const float* __restrict__ wv, const float* __restrict__ wo,
                            u16* __restrict__ wsf) {
  int gid = blockIdx.x * 256 + threadIdx.x;   // [0, 24576)
  int idx, which;
  if (gid < 8192)       { idx = gid;         which = 0; }
  else if (gid < 12288) { idx = gid - 8192;  which = 1; }
  else if (gid < 16384) { idx = gid - 12288; which = 2; }
  else                  { idx = gid - 16384; which = 3; }
  int fragid = idx >> 9, lane = (idx >> 3) & 63, e = idx & 7;
  int l15 = lane & 15, g = lane >> 4;
  float v;
  if (which == 0) {        // wq: [4][128][16]
    int n = fragid >> 2, kc = fragid & 3;
    int c = kc * 32 + g * 8 + e;
    v = wq[n * 2048 + c * 16 + l15] * 0.25f;   // fold D^-0.5
  } else if (which == 1) { // wk: [4][64][16]
    int n = fragid >> 1, kc = fragid & 1;
    int c = kc * 32 + g * 8 + e;
    v = wk[n * 1024 + c * 16 + l15];
  } else if (which == 2) { // wv
    int n = fragid >> 1, kc = fragid & 1;
    int c = kc * 32 + g * 8 + e;
    v = wv[n * 1024 + c * 16 + l15];
  } else {                 // wo: [4][16][128]
    int n8 = fragid >> 1, kc = fragid & 1;
    int hd = kc * 32 + g * 8 + e;
    v = wo[(hd >> 4) * 2048 + (hd & 15) * 128 + n8 * 16 + l15];
  }
  wsf[gid] = bfc(v);
}

#define WQF(n, kc)  ((((n) * 4 + (kc))) * 64)
#define WKF(n, kc)  ((16 + (n) * 2 + (kc)) * 64)
#define WVF(n, kc)  ((24 + (n) * 2 + (kc)) * 64)
#define WOF(n8, kc) ((32 + (n8) * 2 + (kc)) * 64)

typedef const __attribute__((address_space(1))) u32 gas_u32;
typedef __attribute__((address_space(3))) u32 las_u32;

// ---------------------------------------------------------------------------
// Main: 768 blocks x 4 waves. Wave h owns head h. Per tile (16 pos):
// inputs DMA'd to LDS double-buffer (global_load_lds, zero landing VGPRs),
// counted vmcnt(6) + raw barriers, WV exchanged via 2KB LDS for GEMM4.
// ---------------------------------------------------------------------------
__global__ __launch_bounds__(256) void tpa_kernel(
    const float* __restrict__ qe, const float* __restrict__ tpr,
    const float* __restrict__ tmk_p, const float* __restrict__ ob,
    const u16* __restrict__ wsf, float* __restrict__ out)
{
  __shared__ int4 inbuf4[2][1536];   // 2 x 24 KB: [pos][c] qe (8KB) + [t][pos][c] tpr (16KB), XOR-swizzled
  __shared__ u32 wvsh32[512];        // 2 KB WV exchange: [pos][hd] bf16, XOR-swizzled
  char* const inb0 = (char*)inbuf4[0];
  char* const inb1 = (char*)inbuf4[1];
  char* const wvsh = (char*)wvsh32;

  const int tid = threadIdx.x;
  const int wid = tid >> 6;           // wave id = head h
  const int lane = tid & 63;
  const int l15 = lane & 15, g = lane >> 4;
  const int swz = (l15 & 7) << 4;
  const int h = wid;

  // ---- per-lane DMA source bases (inverse-swizzled global addresses) ----
  const char* dmab[6]; int dmstr[6];
  #pragma unroll
  for (int j = 0; j < 6; ++j) {
    int k = wid + 4 * j, m = k * 64 + lane;      // 16B chunk id in [0,1536)
    if (m < 512) {                               // qe region: 8 KB
      int pos = m >> 5, inner = ((m & 31) * 16) ^ ((pos & 7) << 4);
      dmab[j] = (const char*)qe + (size_t)pos * 512 + inner; dmstr[j] = 512;
    } else {                                     // tpr region: 16 KB
      int m2 = m - 512, t = m2 >> 8, pos = (m2 >> 4) & 15;
      int inner = ((m2 & 15) * 16) ^ ((pos & 7) << 4);
      dmab[j] = (const char*)tpr + ((size_t)t * NPOS + pos) * 256 + inner; dmstr[j] = 256;
    }
  }

#define STAGE(DST, P)                                                          \
  { _Pragma("unroll") for (int j = 0; j < 6; ++j) {                            \
      const char* s_ = dmab[j] + (size_t)(P) * dmstr[j];                       \
      char* d_ = (DST) + (wid + 4 * j) * 1024;                                 \
      __builtin_amdgcn_global_load_lds((gas_u32*)s_, (las_u32*)d_, 16, 0, 0); } }

  // ---- prologue: stage tile0, load weights, stage tile1 ----
  STAGE(inb0, blockIdx.x * 16)

  const bf16x8* wf = (const bf16x8*)wsf;
  bf16x8 wqf[4], wkf[2], wvf[2], wof[2][2];
  #pragma unroll
  for (int kc = 0; kc < 4; ++kc) wqf[kc] = wf[WQF(h, kc) + lane];
  #pragma unroll
  for (int kc = 0; kc < 2; ++kc) {
    wkf[kc] = wf[WKF(h, kc) + lane];
    wvf[kc] = wf[WVF(h, kc) + lane];
    wof[0][kc] = wf[WOF(2 * h + 0, kc) + lane];
    wof[1][kc] = wf[WOF(2 * h + 1, kc) + lane];
  }

  const float m0 = tmk_p[0], m1 = tmk_p[1], m2 = tmk_p[2], m3 = tmk_p[3];
  const float biasv[4] = {65504.0f * (m0 - 1.0f), 65504.0f * (m1 - 1.0f),
                          65504.0f * (m2 - 1.0f), 65504.0f * (m3 - 1.0f)};
  const float tmk = (m0 + m1 + m2 + m3 > 0.0f) ? 1.0f : 0.0f;

  f32x4 obf[2];
  {
    const f32x4* obase = reinterpret_cast<const f32x4*>(ob);
    #pragma unroll
    for (int j = 0; j < 2; ++j) {
      const f32x4 o = obase[(2 * h + j) * 4 + g];
      #pragma unroll
      for (int r = 0; r < 4; ++r) obf[j][r] = o[r] * tmk;
    }
  }

  STAGE(inb1, (blockIdx.x + NBLK) * 16)

#define BODY(IT, CB)                                                           \
{                                                                              \
  const int p0 = (blockIdx.x + (IT) * NBLK) * 16;                              \
  __builtin_amdgcn_sched_barrier(0);                                           \
  asm volatile("s_waitcnt vmcnt(6)" ::: "memory");                             \
  __builtin_amdgcn_s_barrier();                                                \
  __builtin_amdgcn_sched_barrier(0);                                           \
  const char* qrow = (CB) + l15 * 512;                                         \
  f32x4 qT = (f32x4){0.f, 0.f, 0.f, 0.f};                                      \
  _Pragma("unroll")                                                            \
  for (int kc = 0; kc < 4; ++kc) {                                             \
    const int cb = kc * 128 + g * 32;                                          \
    f32x4 lo = *(const f32x4*)(qrow + ((cb) ^ swz));                           \
    f32x4 hi = *(const f32x4*)(qrow + ((cb + 16) ^ swz));                      \
    bf16x8 aq;                                                                 \
    _Pragma("unroll")                                                          \
    for (int e = 0; e < 4; ++e) { aq[e] = (short)bfc(lo[e]); aq[e + 4] = (short)bfc(hi[e]); } \
    qT = __builtin_amdgcn_mfma_f32_16x16x32_bf16(wqf[kc], aq, qT, 0, 0, 0);    \
  }                                                                            \
  float ssum = 0.f;                                                            \
  f32x4 wvT = (f32x4){0.f, 0.f, 0.f, 0.f};                                     \
  _Pragma("unroll")                                                            \
  for (int t = 0; t < 4; ++t) {                                                \
    const char* trow = (CB) + 8192 + t * 4096 + l15 * 256;                     \
    bf16x8 at0, at1;                                                           \
    { f32x4 lo = *(const f32x4*)(trow + ((g * 32) ^ swz));                     \
      f32x4 hi = *(const f32x4*)(trow + ((g * 32 + 16) ^ swz));                \
      _Pragma("unroll")                                                        \
      for (int e = 0; e < 4; ++e) { at0[e] = (short)bfc(lo[e]); at0[e + 4] = (short)bfc(hi[e]); } } \
    { f32x4 lo = *(const f32x4*)(trow + ((128 + g * 32) ^ swz));               \
      f32x4 hi = *(const f32x4*)(trow + ((128 + g * 32 + 16) ^ swz));          \
      _Pragma("unroll")                                                        \
      for (int e = 0; e < 4; ++e) { at1[e] = (short)bfc(lo[e]); at1[e + 4] = (short)bfc(hi[e]); } } \
    f32x4 kT = (f32x4){0.f, 0.f, 0.f, 0.f};                                    \
    f32x4 vT = (f32x4){0.f, 0.f, 0.f, 0.f};                                    \
    kT = __builtin_amdgcn_mfma_f32_16x16x32_bf16(wkf[0], at0, kT, 0, 0, 0);    \
    kT = __builtin_amdgcn_mfma_f32_16x16x32_bf16(wkf[1], at1, kT, 0, 0, 0);    \
    vT = __builtin_amdgcn_mfma_f32_16x16x32_bf16(wvf[0], at0, vT, 0, 0, 0);    \
    vT = __builtin_amdgcn_mfma_f32_16x16x32_bf16(wvf[1], at1, vT, 0, 0, 0);    \
    float lg = qT[0] * kT[0] + qT[1] * kT[1] + qT[2] * kT[2] + qT[3] * kT[3];  \
    lg += __shfl_xor(lg, 16);                                                  \
    lg += __shfl_xor(lg, 32);                                                  \
    const float w = __expf(lg + biasv[t]);                                     \
    ssum += w;                                                                 \
    _Pragma("unroll")                                                          \
    for (int r = 0; r < 4; ++r) wvT[r] += w * vT[r];                           \
  }                                                                            \
  { const float inv = tmk / fmaxf(ssum, 1e-30f);                               \
    u32 pk0 = (u32)bfc(wvT[0] * inv) | ((u32)bfc(wvT[1] * inv) << 16);         \
    u32 pk1 = (u32)bfc(wvT[2] * inv) | ((u32)bfc(wvT[3] * inv) << 16);         \
    const int hb = h * 32 + g * 8;                                             \
    *(u32*)(wvsh + ((l15 * 128 + hb) ^ swz))     = pk0;                        \
    *(u32*)(wvsh + ((l15 * 128 + hb + 4) ^ swz)) = pk1; }                      \
  __builtin_amdgcn_sched_barrier(0);                                           \
  asm volatile("s_waitcnt lgkmcnt(0)" ::: "memory");                           \
  __builtin_amdgcn_s_barrier();                                                \
  __builtin_amdgcn_sched_barrier(0);                                           \
  bf16x8 bwv0 = *(const bf16x8*)(wvsh + ((l15 * 128 + g * 16)      ^ swz));    \
  bf16x8 bwv1 = *(const bf16x8*)(wvsh + ((l15 * 128 + 64 + g * 16) ^ swz));    \
  _Pragma("unroll")                                                            \
  for (int j = 0; j < 2; ++j) {                                                \
    f32x4 acc = (f32x4){0.f, 0.f, 0.f, 0.f};                                   \
    acc = __builtin_amdgcn_mfma_f32_16x16x32_bf16(wof[j][0], bwv0, acc, 0, 0, 0); \
    acc = __builtin_amdgcn_mfma_f32_16x16x32_bf16(wof[j][1], bwv1, acc, 0, 0, 0); \
    f32x4 res;                                                                 \
    _Pragma("unroll")                                                          \
    for (int r = 0; r < 4; ++r) res[r] = acc[r] + obf[j][r];                   \
    *(f32x4*)(out + (size_t)(p0 + l15) * 128 + (2 * h + j) * 16 + g * 4) = res; \
  }                                                                            \
  __builtin_amdgcn_sched_barrier(0);                                           \
  { const int sit = ((IT) + 2 < ITERS) ? (IT) + 2 : (IT);                      \
    STAGE(CB, (blockIdx.x + sit * NBLK) * 16) }                                \
}

  for (int ith = 0; ith < ITERS / 2; ++ith) {
    BODY(2 * ith,     inb0)
    BODY(2 * ith + 1, inb1)
  }
}

extern "C" void kernel_launch(void* const* d_in, const int* in_sizes, int n_in,
                              void* d_out, int out_size, void* d_ws, size_t ws_size,
                              hipStream_t stream) {
  const float* qe  = (const float*)d_in[0];
  const float* tpr = (const float*)d_in[1];
  const float* tmk = (const float*)d_in[2];
  const float* wq  = (const float*)d_in[3];
  const float* wk  = (const float*)d_in[4];
  const float* wv  = (const float*)d_in[5];
  const float* wo  = (const float*)d_in[6];
  const float* ob  = (const float*)d_in[7];
  float* out = (float*)d_out;
  u16* wsf = (u16*)d_ws;

  prep_kernel<<<96, 256, 0, stream>>>(wq, wk, wv, wo, wsf);
  tpa_kernel<<<NBLK, 256, 0, stream>>>(qe, tpr, tmk, ob, wsf, out);
}